// Round 12
// baseline (235.056 us; speedup 1.0000x reference)
//
#include <hip/hip_runtime.h>
#include <math.h>

#define IMG 401
#define NKP 17
#define NMID 32
#define CCH 150   // coarse channels: 0-16 kp(sig) | 17-50 so | 51-114 mo | 115-148 lo | 149 ss(sig)

// output region element offsets (f32 elements)
#define OFF_KP   0ULL
#define OFF_SO   5467234ULL
#define OFF_MID  16401702ULL
#define OFF_LONG 36984230ULL
#define OFF_SS   47918698ULL
// total out_size = 48,240,300 f32

#define SCc (13.0f/401.0f)
#define C0c (13.0f/802.0f - 0.5f)

typedef float v2f __attribute__((ext_vector_type(2)));

// statics: rewritten fully every call before being read
__device__ float  g_coarse[2 * 169 * CCH];
// field-planar pairs: [n][66 fields][169 cells] float2; fields 0-16=so,17-48=mo,49-65=lo
__device__ float2 g_pairs[2 * 66 * 169];

__constant__ int TO_KP_C[32] = {1,3,2,4,5,7,9,11,13,15,6,8,10,12,14,16,
                                0,1,0,2,0,5,7,5,11,13,0,6,8,6,12,14};

__device__ __forceinline__ float med3(float a, float b, float c) {
  return __builtin_amdgcn_fmed3f(a, b, c);
}
__device__ __forceinline__ void store2(float* p, float a, float b) {
  *reinterpret_cast<float2*>(p) = make_float2(a, b);   // 8B-aligned by construction
}
__device__ __forceinline__ v2f ldb(const float2* p, int byteoff) {
  return *reinterpret_cast<const v2f*>(reinterpret_cast<const char*>(p) + byteoff);
}

// ---------------- kernel 1: heads GEMM, 3-way K-split, 4 indep accumulators ---------------
__global__ __launch_bounds__(512)
void heads_kernel(const float* __restrict__ x,
                  const float* __restrict__ kp_w, const float* __restrict__ kp_b,
                  const float* __restrict__ so_w, const float* __restrict__ so_b,
                  const float* __restrict__ mo_w, const float* __restrict__ mo_b,
                  const float* __restrict__ lo_w, const float* __restrict__ lo_b,
                  const float* __restrict__ ss_w, const float* __restrict__ ss_b) {
  __shared__ __align__(16) float xs[2048];
  __shared__ float ps[300];
  const int pix = blockIdx.x;                 // 0..337  (= n*169 + p)
  const int tid = threadIdx.x;
  const float* xr = x + (size_t)pix * 2048;
  for (int t = tid; t < 2048; t += 512) xs[t] = xr[t];
  __syncthreads();
  const int part = tid / 150;                 // 0..3 (part 3 idle)
  const int c = tid - part * 150;
  float acc = 0.f;
  const float* bptr = nullptr; int cc = 0; bool sig = false;
  if (part < 3) {
    const float* wptr; int Ch;
    if (c < 17)       { wptr = kp_w; bptr = kp_b; Ch = 17; cc = c;       sig = true; }
    else if (c < 51)  { wptr = so_w; bptr = so_b; Ch = 34; cc = c - 17; }
    else if (c < 115) { wptr = mo_w; bptr = mo_b; Ch = 64; cc = c - 51; }
    else if (c < 149) { wptr = lo_w; bptr = lo_b; Ch = 34; cc = c - 115; }
    else              { wptr = ss_w; bptr = ss_b; Ch = 1;  cc = 0;       sig = true; }
    const float* wp = wptr + cc;
    const int k0 = part * 684;                 // 684/684/680, all %4==0 (16B-aligned)
    const int k1 = (part == 2) ? 2048 : (k0 + 684);
    float a0 = 0.f, a1 = 0.f, a2 = 0.f, a3 = 0.f;
    #pragma unroll 4
    for (int k = k0; k < k1; k += 4) {
      float4 xv = *reinterpret_cast<const float4*>(&xs[k]);
      a0 = fmaf(xv.x, wp[(k    ) * Ch], a0);
      a1 = fmaf(xv.y, wp[(k + 1) * Ch], a1);
      a2 = fmaf(xv.z, wp[(k + 2) * Ch], a2);
      a3 = fmaf(xv.w, wp[(k + 3) * Ch], a3);
    }
    acc = (a0 + a1) + (a2 + a3);
    if (part) ps[c + (part - 1) * 150] = acc;
  }
  __syncthreads();
  if (part == 0) {
    acc += ps[c] + ps[c + 150] + bptr[cc];
    if (sig) acc = 1.0f / (1.0f + expf(-acc));
    g_coarse[(size_t)pix * CCH + c] = acc;
    if (c >= 17 && c < 149) {
      int rel = c - 17;
      int nn = pix / 169, pp = pix - nn * 169;
      ((float*)g_pairs)[(((size_t)nn * 66 + (rel >> 1)) * 169 + pp) * 2 + (rel & 1)] = acc;
    }
  }
}

// ---------------- per-pixel context (x/y packed) -------------------------------------------
struct Pix {
  v2f Q0, Q1;      // bilerp weights {q00,q01},{q10,q11}
  v2f SWH;         // unclamped coarse coords of (w,h)
  v2f LOV;         // {-w, -h}
  v2f HIV;         // {400-w, 400-h}
  int ob;          // byte offset of cell (py0,px0) in a 13x13 float2 plane
  int pix;
  bool valid;
};

__device__ __forceinline__ Pix mkpix(int n, int w, int h) {
  Pix P;
  P.valid = (w < IMG) && (h < IMG);
  v2f WH = {(float)w, (float)h};
  v2f S = WH * SCc + C0c;
  float cx = med3(floorf(S.x), 0.f, 11.f);    // == min(floor(clamp(s,0,12)),11)
  float cy = med3(floorf(S.y), 0.f, 11.f);
  float fx = med3(S.x - cx, 0.f, 1.f);        // exact (Sterbenz) frac, clamp-extended
  float fy = med3(S.y - cy, 0.f, 1.f);
  float gx = 1.f - fx, gy = 1.f - fy;
  P.Q0 = (v2f){gx, fx} * gy;
  P.Q1 = (v2f){gx, fx} * fy;
  P.ob = (int)fmaf(cy, 104.f, cx * 8.f);
  P.SWH = S;
  P.LOV = -WH;
  P.HIV = 400.f - WH;
  P.pix = (n * IMG + h) * IMG + w;
  return P;
}

__device__ __forceinline__ v2f blp4b(const float2* __restrict__ F, const Pix& P) {
  return P.Q0.x * ldb(F, P.ob)       + P.Q0.y * ldb(F, P.ob + 8)
       + P.Q1.x * ldb(F, P.ob + 104) + P.Q1.y * ldb(F, P.ob + 112);
}

// ----- 3x3-footprint bilinear_sampler, x/y axes packed into v2f lanes ----------------------
__device__ __forceinline__ v2f samplePk(const float2* __restrict__ F, v2f v, const Pix& P) {
  v2f F0 = {floorf(v.x), floorf(v.y)};
  v2f D  = v - F0;
  v2f E  = {D.x > 0.f ? 1.f : 0.f, D.y > 0.f ? 1.f : 0.f};
  v2f J1 = F0 + E;
  float sel = (F0.x < P.LOV.x || F0.y < P.LOV.y ||
               J1.x > P.HIV.x || J1.y > P.HIV.y) ? 0.f : 1.f;
  v2f S0 = F0 * SCc + P.SWH;
  v2f S1 = E  * SCc + S0;
  v2f C0 = {med3(floorf(S0.x), 0.f, 11.f), med3(floorf(S0.y), 0.f, 11.f)};
  v2f C1 = {med3(floorf(S1.x), 0.f, 11.f), med3(floorf(S1.y), 0.f, 11.f)};
  v2f U0t = S0 - C0;
  v2f U0 = {med3(U0t.x, 0.f, 1.f), med3(U0t.y, 0.f, 1.f)};
  v2f U1t = S1 - C1;
  v2f U1 = {med3(U1t.x, 0.f, 1.f), med3(U1t.y, 0.f, 1.f)};
  v2f DD = C1 - C0;                         // exactly 0 or 1 per axis
  v2f G  = 1.f - D;
  v2f E0 = G * U0;
  v2f E1 = D * U1;
  v2f Fd = D - E1;
  v2f M  = Fd - Fd * DD;
  v2f W0 = (G - E0) + M;                    // {W0_x, V0_y}
  v2f Tt = Fd - E1;
  v2f W1 = (E0 + E1) + Tt * DD;             // {W1_x, V1_y}
  v2f W2 = E1 * DD;                         // {W2_x, V2_y}
  int a = (int)fmaf(C0.y, 104.f, C0.x * 8.f);
  v2f r0 = W0.x*ldb(F,a)     + W1.x*ldb(F,a+8)   + W2.x*ldb(F,a+16);
  v2f r1 = W0.x*ldb(F,a+104) + W1.x*ldb(F,a+112) + W2.x*ldb(F,a+120);
  v2f r2 = W0.x*ldb(F,a+208) + W1.x*ldb(F,a+216) + W2.x*ldb(F,a+224);
  v2f acc = W0.y*r0 + W1.y*r1 + W2.y*r2;
  return acc * sel;
}

// ---------------- work items --------------------------------------------------------------
__device__ __forceinline__ void kp_item(int f, int n, int w0, int h0,
                                        const float* __restrict__ cb,
                                        float* __restrict__ out) {
  int r = f / 544, rem = f - r * 544;
  int px = rem / 17, c = rem - px * 17;
  Pix P = mkpix(n, w0 + px, h0 + r);
  if (P.valid) {
    const float* b0 = cb + (P.ob >> 3) * CCH + c;
    float v = P.Q0.x*b0[0] + P.Q0.y*b0[CCH] + P.Q1.x*b0[13*CCH] + P.Q1.y*b0[14*CCH];
    out[OFF_KP + (size_t)P.pix * 17 + c] = v;
  }
}

__device__ __forceinline__ void solong_item(int f, int n, int w0, int h0,
                                            const float2* __restrict__ Sf,
                                            const float2* __restrict__ Lf,
                                            float* __restrict__ out) {
  int r = f / 544, rem = f - r * 544;
  int px = rem / 17, k = rem - px * 17;
  Pix P = mkpix(n, w0 + px, h0 + r);
  const float2* S = Sf + k * 169;
  const float2* L = Lf + k * 169;
  v2f sv = blp4b(S, P);
  v2f b  = blp4b(L, P);
  b += samplePk(L, b, P);
  b += samplePk(L, b, P);
  b += samplePk(S, b, P);
  b += samplePk(S, b, P);
  if (P.valid) {
    store2(out + OFF_SO   + (size_t)P.pix * 34 + 2 * k, sv.x, sv.y);
    store2(out + OFF_LONG + (size_t)P.pix * 34 + 2 * k, b.x, b.y);
  }
}

__device__ __forceinline__ void mid_item(int f, int n, int w0, int h0,
                                         const float2* __restrict__ Sf,
                                         const float2* __restrict__ gmo,
                                         float* __restrict__ out) {
  int r = f >> 10, rem = f & 1023;
  int px = rem >> 5, g = rem & 31;
  Pix P = mkpix(n, w0 + px, h0 + r);
  const float2* G = gmo + g * 169;
  v2f b = blp4b(G, P);
  const float2* S = Sf + TO_KP_C[g] * 169;
  b += samplePk(S, b, P);
  b += samplePk(S, b, P);
  if (P.valid) store2(out + OFF_MID + (size_t)P.pix * 64 + 2 * g, b.x, b.y);
}

// ---------------- kernel 2: element-remapped, packed 3x3 sampler -------------------------
__global__ __launch_bounds__(512, 6)
void refine512_kernel(float* __restrict__ out) {
  __shared__ float2 Sf[NKP * 169 + 14];   // +14 zeroed pad: 3x3 window overshoot
  __shared__ float2 Lf[NKP * 169 + 14];
  const int n = blockIdx.z;
  const int tid = threadIdx.x;
  const int w0 = blockIdx.x * 32, h0 = blockIdx.y * 16;

  {
    const float2* gS = g_pairs + (size_t)n * 66 * 169;
    const float2* gL = g_pairs + ((size_t)n * 66 + 49) * 169;
    for (int t = tid; t < NKP * 169; t += 512) { Sf[t] = gS[t]; Lf[t] = gL[t]; }
    if (tid < 14) {
      Sf[NKP * 169 + tid] = make_float2(0.f, 0.f);
      Lf[NKP * 169 + tid] = make_float2(0.f, 0.f);
    }
  }
  __syncthreads();

  const float* cb = g_coarse + (size_t)n * 169 * CCH;

  // ---- kp: 16*32*17 = 8704 elements ----
  #pragma unroll 1
  for (int it = 0; it < 8; ++it) {
    kp_item(it * 512 + tid, n, w0, h0, cb, out);
    kp_item((it + 8) * 512 + tid, n, w0, h0, cb, out);
  }
  kp_item(16 * 512 + tid, n, w0, h0, cb, out);

  // ---- ss: 512 elements ----
  {
    int r = tid >> 5, px = tid & 31;
    Pix P = mkpix(n, w0 + px, h0 + r);
    if (P.valid) {
      const float* b0 = cb + (P.ob >> 3) * CCH + 149;
      out[OFF_SS + (size_t)P.pix] =
          P.Q0.x*b0[0] + P.Q0.y*b0[CCH] + P.Q1.x*b0[13*CCH] + P.Q1.y*b0[14*CCH];
    }
  }

  // ---- so + long: 8704 pairs ----
  #pragma unroll 1
  for (int it = 0; it < 8; ++it) {
    solong_item(it * 512 + tid, n, w0, h0, Sf, Lf, out);
    solong_item((it + 8) * 512 + tid, n, w0, h0, Sf, Lf, out);
  }
  solong_item(16 * 512 + tid, n, w0, h0, Sf, Lf, out);

  // ---- mid: 16384 pairs ----
  const float2* gmo = g_pairs + ((size_t)n * 66 + 17) * 169;
  #pragma unroll 1
  for (int it = 0; it < 16; ++it) {
    mid_item(it * 512 + tid, n, w0, h0, Sf, gmo, out);
    mid_item((it + 16) * 512 + tid, n, w0, h0, Sf, gmo, out);
  }
}

extern "C" void kernel_launch(void* const* d_in, const int* in_sizes, int n_in,
                              void* d_out, int out_size, void* d_ws, size_t ws_size,
                              hipStream_t stream) {
  const float* x    = (const float*)d_in[0];
  const float* kp_w = (const float*)d_in[1];
  const float* kp_b = (const float*)d_in[2];
  const float* so_w = (const float*)d_in[3];
  const float* so_b = (const float*)d_in[4];
  const float* mo_w = (const float*)d_in[5];
  const float* mo_b = (const float*)d_in[6];
  const float* lo_w = (const float*)d_in[7];
  const float* lo_b = (const float*)d_in[8];
  const float* ss_w = (const float*)d_in[9];
  const float* ss_b = (const float*)d_in[10];
  float* out = (float*)d_out;

  heads_kernel<<<dim3(338), dim3(512), 0, stream>>>(x, kp_w, kp_b, so_w, so_b,
                                                    mo_w, mo_b, lo_w, lo_b,
                                                    ss_w, ss_b);
  refine512_kernel<<<dim3(13, 26, 2), dim3(512), 0, stream>>>(out);
}

// Round 13
// 170.218 us; speedup vs baseline: 1.3809x; 1.3809x over previous
//
#include <hip/hip_runtime.h>
#include <math.h>

#define IMG 401
#define NKP 17
#define NMID 32
#define CCH 150   // coarse channels: 0-16 kp(sig) | 17-50 so | 51-114 mo | 115-148 lo | 149 ss(sig)

// output region element offsets (f32 elements)
#define OFF_KP   0ULL
#define OFF_SO   5467234ULL
#define OFF_MID  16401702ULL
#define OFF_LONG 36984230ULL
#define OFF_SS   47918698ULL
// total out_size = 48,240,300 f32

#define SCc (13.0f/401.0f)
#define C0c (13.0f/802.0f - 0.5f)

typedef float v2f __attribute__((ext_vector_type(2)));

// statics: rewritten fully every call before being read
__device__ float  g_coarse[2 * 169 * CCH];
// field-planar pairs: [n][66 fields][169 cells] float2; fields 0-16=so,17-48=mo,49-65=lo
__device__ float2 g_pairs[2 * 66 * 169];

__constant__ int TO_KP_C[32] = {1,3,2,4,5,7,9,11,13,15,6,8,10,12,14,16,
                                0,1,0,2,0,5,7,5,11,13,0,6,8,6,12,14};

__device__ __forceinline__ float med3(float a, float b, float c) {
  return __builtin_amdgcn_fmed3f(a, b, c);
}
__device__ __forceinline__ void store2(float* p, float a, float b) {
  *reinterpret_cast<float2*>(p) = make_float2(a, b);   // 8B-aligned by construction
}
__device__ __forceinline__ v2f ldb(const float2* p, int byteoff) {
  return *reinterpret_cast<const v2f*>(reinterpret_cast<const char*>(p) + byteoff);
}

// ---------------- kernel 1: heads GEMM, 2 pixels/block share each weight load -------------
// (round-11 inner loop structure: ptr-walk weight load + simple fma chain; ILP from 2 pixels)
__global__ __launch_bounds__(512)
void heads_kernel(const float* __restrict__ x,
                  const float* __restrict__ kp_w, const float* __restrict__ kp_b,
                  const float* __restrict__ so_w, const float* __restrict__ so_b,
                  const float* __restrict__ mo_w, const float* __restrict__ mo_b,
                  const float* __restrict__ lo_w, const float* __restrict__ lo_b,
                  const float* __restrict__ ss_w, const float* __restrict__ ss_b) {
  __shared__ float xs[2][2048];
  __shared__ float ps[2][300];
  const int p0 = blockIdx.x * 2;              // pixels p0, p0+1 (338 = 2*169)
  const int tid = threadIdx.x;
  const float* xr = x + (size_t)p0 * 2048;    // two consecutive rows = 4096 floats
  for (int t = tid; t < 4096; t += 512) xs[t >> 11][t & 2047] = xr[t];
  __syncthreads();
  const int part = tid / 150;                 // 0..3 (part 3 idle)
  const int c = tid - part * 150;
  float a0 = 0.f, a1 = 0.f;
  const float* bptr = nullptr; int cc = 0; bool sig = false;
  if (part < 3) {
    const float* wptr; int Ch;
    if (c < 17)       { wptr = kp_w; bptr = kp_b; Ch = 17; cc = c;       sig = true; }
    else if (c < 51)  { wptr = so_w; bptr = so_b; Ch = 34; cc = c - 17; }
    else if (c < 115) { wptr = mo_w; bptr = mo_b; Ch = 64; cc = c - 51; }
    else if (c < 149) { wptr = lo_w; bptr = lo_b; Ch = 34; cc = c - 115; }
    else              { wptr = ss_w; bptr = ss_b; Ch = 1;  cc = 0;       sig = true; }
    const float* wp = wptr + cc;
    const int k0 = part * 683, k1 = (part == 2) ? 2048 : (k0 + 683);
    #pragma unroll 8
    for (int k = k0; k < k1; ++k) {
      float wv = wp[k * Ch];
      a0 = fmaf(xs[0][k], wv, a0);
      a1 = fmaf(xs[1][k], wv, a1);
    }
    if (part) { ps[0][c + (part - 1) * 150] = a0; ps[1][c + (part - 1) * 150] = a1; }
  }
  __syncthreads();
  if (part == 0) {
    float b = bptr[cc];
    float v0 = a0 + ps[0][c] + ps[0][c + 150] + b;
    float v1 = a1 + ps[1][c] + ps[1][c + 150] + b;
    if (sig) { v0 = 1.0f / (1.0f + expf(-v0)); v1 = 1.0f / (1.0f + expf(-v1)); }
    g_coarse[(size_t)p0 * CCH + c] = v0;
    g_coarse[(size_t)(p0 + 1) * CCH + c] = v1;
    if (c >= 17 && c < 149) {
      int rel = c - 17;
      int fi = rel >> 1, lo = rel & 1;
      int nn0 = p0 / 169, pp0 = p0 - nn0 * 169;
      int nn1 = (p0 + 1) / 169, pp1 = (p0 + 1) - nn1 * 169;
      ((float*)g_pairs)[(((size_t)nn0 * 66 + fi) * 169 + pp0) * 2 + lo] = v0;
      ((float*)g_pairs)[(((size_t)nn1 * 66 + fi) * 169 + pp1) * 2 + lo] = v1;
    }
  }
}

// ---------------- per-pixel context (x/y packed) -------------------------------------------
struct Pix {
  v2f Q0, Q1;      // bilerp weights {q00,q01},{q10,q11}
  v2f SWH;         // unclamped coarse coords of (w,h)
  v2f LOV;         // {-w, -h}
  v2f HIV;         // {400-w, 400-h}
  int ob;          // byte offset of cell (py0,px0) in a 13x13 float2 plane
  int pix;
  bool valid;
};

__device__ __forceinline__ Pix mkpix(int n, int w, int h) {
  Pix P;
  P.valid = (w < IMG) && (h < IMG);
  v2f WH = {(float)w, (float)h};
  v2f S = WH * SCc + C0c;
  float cx = med3(floorf(S.x), 0.f, 11.f);    // == min(floor(clamp(s,0,12)),11)
  float cy = med3(floorf(S.y), 0.f, 11.f);
  float fx = med3(S.x - cx, 0.f, 1.f);        // exact (Sterbenz) frac, clamp-extended
  float fy = med3(S.y - cy, 0.f, 1.f);
  float gx = 1.f - fx, gy = 1.f - fy;
  P.Q0 = (v2f){gx, fx} * gy;
  P.Q1 = (v2f){gx, fx} * fy;
  P.ob = (int)fmaf(cy, 104.f, cx * 8.f);
  P.SWH = S;
  P.LOV = -WH;
  P.HIV = 400.f - WH;
  P.pix = (n * IMG + h) * IMG + w;
  return P;
}

__device__ __forceinline__ v2f blp4b(const float2* __restrict__ F, const Pix& P) {
  return P.Q0.x * ldb(F, P.ob)       + P.Q0.y * ldb(F, P.ob + 8)
       + P.Q1.x * ldb(F, P.ob + 104) + P.Q1.y * ldb(F, P.ob + 112);
}

// ----- 3x3-footprint bilinear_sampler, x/y axes packed into v2f lanes ----------------------
__device__ __forceinline__ v2f samplePk(const float2* __restrict__ F, v2f v, const Pix& P) {
  v2f F0 = {floorf(v.x), floorf(v.y)};
  v2f D  = v - F0;
  v2f E  = {D.x > 0.f ? 1.f : 0.f, D.y > 0.f ? 1.f : 0.f};
  v2f J1 = F0 + E;
  float sel = (F0.x < P.LOV.x || F0.y < P.LOV.y ||
               J1.x > P.HIV.x || J1.y > P.HIV.y) ? 0.f : 1.f;
  v2f S0 = F0 * SCc + P.SWH;
  v2f S1 = E  * SCc + S0;
  v2f C0 = {med3(floorf(S0.x), 0.f, 11.f), med3(floorf(S0.y), 0.f, 11.f)};
  v2f C1 = {med3(floorf(S1.x), 0.f, 11.f), med3(floorf(S1.y), 0.f, 11.f)};
  v2f U0t = S0 - C0;
  v2f U0 = {med3(U0t.x, 0.f, 1.f), med3(U0t.y, 0.f, 1.f)};
  v2f U1t = S1 - C1;
  v2f U1 = {med3(U1t.x, 0.f, 1.f), med3(U1t.y, 0.f, 1.f)};
  v2f DD = C1 - C0;                         // exactly 0 or 1 per axis
  v2f G  = 1.f - D;
  v2f E0 = G * U0;
  v2f E1 = D * U1;
  v2f Fd = D - E1;
  v2f M  = Fd - Fd * DD;
  v2f W0 = (G - E0) + M;                    // {W0_x, V0_y}
  v2f Tt = Fd - E1;
  v2f W1 = (E0 + E1) + Tt * DD;             // {W1_x, V1_y}
  v2f W2 = E1 * DD;                         // {W2_x, V2_y}
  int a = (int)fmaf(C0.y, 104.f, C0.x * 8.f);
  v2f r0 = W0.x*ldb(F,a)     + W1.x*ldb(F,a+8)   + W2.x*ldb(F,a+16);
  v2f r1 = W0.x*ldb(F,a+104) + W1.x*ldb(F,a+112) + W2.x*ldb(F,a+120);
  v2f r2 = W0.x*ldb(F,a+208) + W1.x*ldb(F,a+216) + W2.x*ldb(F,a+224);
  v2f acc = W0.y*r0 + W1.y*r1 + W2.y*r2;
  return acc * sel;
}

// ---------------- work items --------------------------------------------------------------
__device__ __forceinline__ void kp_item(int f, int n, int w0, int h0,
                                        const float* __restrict__ cb,
                                        float* __restrict__ out) {
  int r = f / 544, rem = f - r * 544;
  int px = rem / 17, c = rem - px * 17;
  Pix P = mkpix(n, w0 + px, h0 + r);
  if (P.valid) {
    const float* b0 = cb + (P.ob >> 3) * CCH + c;
    float v = P.Q0.x*b0[0] + P.Q0.y*b0[CCH] + P.Q1.x*b0[13*CCH] + P.Q1.y*b0[14*CCH];
    out[OFF_KP + (size_t)P.pix * 17 + c] = v;
  }
}

__device__ __forceinline__ void solong_item(int f, int n, int w0, int h0,
                                            const float2* __restrict__ Sf,
                                            const float2* __restrict__ Lf,
                                            float* __restrict__ out) {
  int r = f / 544, rem = f - r * 544;
  int px = rem / 17, k = rem - px * 17;
  Pix P = mkpix(n, w0 + px, h0 + r);
  const float2* S = Sf + k * 169;
  const float2* L = Lf + k * 169;
  v2f sv = blp4b(S, P);
  v2f b  = blp4b(L, P);
  b += samplePk(L, b, P);
  b += samplePk(L, b, P);
  b += samplePk(S, b, P);
  b += samplePk(S, b, P);
  if (P.valid) {
    store2(out + OFF_SO   + (size_t)P.pix * 34 + 2 * k, sv.x, sv.y);
    store2(out + OFF_LONG + (size_t)P.pix * 34 + 2 * k, b.x, b.y);
  }
}

__device__ __forceinline__ void mid_item(int f, int n, int w0, int h0,
                                         const float2* __restrict__ Sf,
                                         const float2* __restrict__ gmo,
                                         float* __restrict__ out) {
  int r = f >> 10, rem = f & 1023;
  int px = rem >> 5, g = rem & 31;
  Pix P = mkpix(n, w0 + px, h0 + r);
  const float2* G = gmo + g * 169;
  v2f b = blp4b(G, P);
  const float2* S = Sf + TO_KP_C[g] * 169;
  b += samplePk(S, b, P);
  b += samplePk(S, b, P);
  if (P.valid) store2(out + OFF_MID + (size_t)P.pix * 64 + 2 * g, b.x, b.y);
}

// ---------------- kernel 2: element-remapped, packed 3x3 sampler, deep ILP ----------------
__global__ __launch_bounds__(512, 6)
void refine512_kernel(float* __restrict__ out) {
  __shared__ float2 Sf[NKP * 169 + 14];   // +14 zeroed pad: 3x3 window overshoot
  __shared__ float2 Lf[NKP * 169 + 14];
  const int n = blockIdx.z;
  const int tid = threadIdx.x;
  const int w0 = blockIdx.x * 32, h0 = blockIdx.y * 16;

  {
    const float2* gS = g_pairs + (size_t)n * 66 * 169;
    const float2* gL = g_pairs + ((size_t)n * 66 + 49) * 169;
    for (int t = tid; t < NKP * 169; t += 512) { Sf[t] = gS[t]; Lf[t] = gL[t]; }
    if (tid < 14) {
      Sf[NKP * 169 + tid] = make_float2(0.f, 0.f);
      Lf[NKP * 169 + tid] = make_float2(0.f, 0.f);
    }
  }
  __syncthreads();

  const float* cb = g_coarse + (size_t)n * 169 * CCH;

  // ---- kp: 16*32*17 = 8704 elements (ILP-4) ----
  #pragma unroll 1
  for (int it = 0; it < 4; ++it) {
    kp_item(it * 512 + tid, n, w0, h0, cb, out);
    kp_item((it + 4) * 512 + tid, n, w0, h0, cb, out);
    kp_item((it + 8) * 512 + tid, n, w0, h0, cb, out);
    kp_item((it + 12) * 512 + tid, n, w0, h0, cb, out);
  }
  kp_item(16 * 512 + tid, n, w0, h0, cb, out);

  // ---- ss: 512 elements ----
  {
    int r = tid >> 5, px = tid & 31;
    Pix P = mkpix(n, w0 + px, h0 + r);
    if (P.valid) {
      const float* b0 = cb + (P.ob >> 3) * CCH + 149;
      out[OFF_SS + (size_t)P.pix] =
          P.Q0.x*b0[0] + P.Q0.y*b0[CCH] + P.Q1.x*b0[13*CCH] + P.Q1.y*b0[14*CCH];
    }
  }

  // ---- so + long: 8704 pairs (ILP-3 x5 then ILP-2) ----
  #pragma unroll 1
  for (int it = 0; it < 5; ++it) {
    solong_item(it * 512 + tid, n, w0, h0, Sf, Lf, out);
    solong_item((it + 5) * 512 + tid, n, w0, h0, Sf, Lf, out);
    solong_item((it + 10) * 512 + tid, n, w0, h0, Sf, Lf, out);
  }
  solong_item(15 * 512 + tid, n, w0, h0, Sf, Lf, out);
  solong_item(16 * 512 + tid, n, w0, h0, Sf, Lf, out);

  // ---- mid: 16384 pairs (ILP-4) ----
  const float2* gmo = g_pairs + ((size_t)n * 66 + 17) * 169;
  #pragma unroll 1
  for (int it = 0; it < 8; ++it) {
    mid_item(it * 512 + tid, n, w0, h0, Sf, gmo, out);
    mid_item((it + 8) * 512 + tid, n, w0, h0, Sf, gmo, out);
    mid_item((it + 16) * 512 + tid, n, w0, h0, Sf, gmo, out);
    mid_item((it + 24) * 512 + tid, n, w0, h0, Sf, gmo, out);
  }
}

extern "C" void kernel_launch(void* const* d_in, const int* in_sizes, int n_in,
                              void* d_out, int out_size, void* d_ws, size_t ws_size,
                              hipStream_t stream) {
  const float* x    = (const float*)d_in[0];
  const float* kp_w = (const float*)d_in[1];
  const float* kp_b = (const float*)d_in[2];
  const float* so_w = (const float*)d_in[3];
  const float* so_b = (const float*)d_in[4];
  const float* mo_w = (const float*)d_in[5];
  const float* mo_b = (const float*)d_in[6];
  const float* lo_w = (const float*)d_in[7];
  const float* lo_b = (const float*)d_in[8];
  const float* ss_w = (const float*)d_in[9];
  const float* ss_b = (const float*)d_in[10];
  float* out = (float*)d_out;

  heads_kernel<<<dim3(169), dim3(512), 0, stream>>>(x, kp_w, kp_b, so_w, so_b,
                                                    mo_w, mo_b, lo_w, lo_b,
                                                    ss_w, ss_b);
  refine512_kernel<<<dim3(13, 26, 2), dim3(512), 0, stream>>>(out);
}